// Round 2
// baseline (137.712 us; speedup 1.0000x reference)
//
#include <hip/hip_runtime.h>
#include <hip/hip_bf16.h>
#include <stdint.h>

// Problem constants (B=8, S=512, D=1024)
constexpr int N_TOK  = 4096;   // B*S
constexpr int D_DIM  = 1024;
constexpr int MASK_ID_V = 8192;

// Tiling
constexpr int BM     = 128;    // rows (embedding) per block
constexpr int BN     = 128;    // cols (keys) per col-tile
constexpr int BK     = 64;     // K-slice per stage
constexpr int NSLICE = 8;      // column slices across grid.y
constexpr int SLICE_W = N_TOK / NSLICE;      // 512
constexpr int CTS    = SLICE_W / BN;         // 4 col-tiles per block
constexpr int KSTEPS = D_DIM / BK;           // 16
constexpr int LDW    = BK + 8;               // padded LDS row (ushorts): 144B stride
constexpr int NPART  = NSLICE * 2;           // 16 partials per row (2 wc-waves per slice)

typedef __attribute__((ext_vector_type(4))) float f32x4;
typedef __attribute__((ext_vector_type(8))) short bf16x8;

__device__ __forceinline__ uint32_t pk2bf(float lo, float hi) {
    // round-to-nearest-even fp32 -> bf16, packed pair
    union { float f; uint32_t u; } a, b;
    a.f = lo; b.f = hi;
    uint32_t ua = (a.u + 0x7fffu + ((a.u >> 16) & 1u)) >> 16;
    uint32_t ub = (b.u + 0x7fffu + ((b.u >> 16) & 1u)) >> 16;
    return ua | (ub << 16);
}

// Main kernel: scores tile GEMM (bf16 MFMA) + online per-lane softmax partials
__global__ __launch_bounds__(256, 2) void nce_gemm_lse(
    const float* __restrict__ x,      // [N_TOK, D] keys
    const float* __restrict__ emb,    // [N_TOK, D] queries
    float* __restrict__ numer,        // [N_TOK]
    float* __restrict__ pm,           // [N_TOK, NPART] partial max
    float* __restrict__ ps)           // [N_TOK, NPART] partial sumexp
{
    __shared__ ushort At[BM][LDW];
    __shared__ ushort Bt[BN][LDW];

    const int rb   = blockIdx.x;          // 0..31
    const int cs   = blockIdx.y;          // 0..7
    const int row0 = rb * BM;
    const int col0 = cs * SLICE_W;

    const int tid  = threadIdx.x;
    const int lane = tid & 63;
    const int wid  = tid >> 6;
    const int wr   = wid >> 1;            // wave row 0..1
    const int wc   = wid & 1;             // wave col 0..1
    const int l15  = lane & 15;
    const int lhi  = lane >> 4;           // 0..3

    // Running (m, s) per (mi, r): rows this lane contributes to.
    float m_run[16], s_run[16];
#pragma unroll
    for (int i = 0; i < 16; ++i) { m_run[i] = -3.0e38f; s_run[i] = 0.0f; }

    for (int ct = 0; ct < CTS; ++ct) {
        const int colt0 = col0 + ct * BN;

        f32x4 acc[4][4];
#pragma unroll
        for (int a = 0; a < 4; ++a)
#pragma unroll
            for (int b = 0; b < 4; ++b)
                acc[a][b] = f32x4{0.f, 0.f, 0.f, 0.f};

#pragma unroll 1
        for (int kt = 0; kt < KSTEPS; ++kt) {
            __syncthreads();   // protect LDS from previous iteration's readers
            // Stage A (emb rows) and B (x rows) k-slices: fp32 -> bf16 -> LDS.
            // 1024 16B-chunks per tile; 4 chunks/thread/tile.
#pragma unroll
            for (int i = 0; i < 4; ++i) {
                const int chunk = tid + i * 256;       // 0..1023
                const int r  = chunk >> 3;             // 0..127
                const int c8 = (chunk & 7) << 3;       // 0..56 step 8

                const float* ga = emb + (size_t)(row0 + r) * D_DIM + kt * BK + c8;
                float4 a0 = *(const float4*)(ga);
                float4 a1 = *(const float4*)(ga + 4);
                uint4 pa;
                pa.x = pk2bf(a0.x, a0.y); pa.y = pk2bf(a0.z, a0.w);
                pa.z = pk2bf(a1.x, a1.y); pa.w = pk2bf(a1.z, a1.w);
                *(uint4*)&At[r][c8] = pa;

                const float* gb = x + (size_t)(colt0 + r) * D_DIM + kt * BK + c8;
                float4 b0 = *(const float4*)(gb);
                float4 b1 = *(const float4*)(gb + 4);
                uint4 pb;
                pb.x = pk2bf(b0.x, b0.y); pb.y = pk2bf(b0.z, b0.w);
                pb.z = pk2bf(b1.x, b1.y); pb.w = pk2bf(b1.z, b1.w);
                *(uint4*)&Bt[r][c8] = pb;
            }
            __syncthreads();

#pragma unroll
            for (int kp = 0; kp < 2; ++kp) {
                const int ko = kp * 32 + lhi * 8;
                bf16x8 af[4], bfr[4];
#pragma unroll
                for (int mi = 0; mi < 4; ++mi)
                    af[mi] = *(const bf16x8*)&At[wr * 64 + mi * 16 + l15][ko];
#pragma unroll
                for (int ni = 0; ni < 4; ++ni)
                    bfr[ni] = *(const bf16x8*)&Bt[wc * 64 + ni * 16 + l15][ko];
#pragma unroll
                for (int mi = 0; mi < 4; ++mi)
#pragma unroll
                    for (int ni = 0; ni < 4; ++ni)
                        acc[mi][ni] = __builtin_amdgcn_mfma_f32_16x16x32_bf16(
                            af[mi], bfr[ni], acc[mi][ni], 0, 0, 0);
            }
        } // kt

        // Diagonal extraction: numer[i] = scores[i][i]
#pragma unroll
        for (int mi = 0; mi < 4; ++mi)
#pragma unroll
            for (int r = 0; r < 4; ++r) {
                const int row_g = row0 + wr * 64 + mi * 16 + lhi * 4 + r;
#pragma unroll
                for (int ni = 0; ni < 4; ++ni) {
                    const int col_g = colt0 + wc * 64 + ni * 16 + l15;
                    if (row_g == col_g) numer[row_g] = acc[mi][ni][r];
                }
            }

        // Online softmax update (per-lane, no shuffles in hot path)
#pragma unroll
        for (int mi = 0; mi < 4; ++mi)
#pragma unroll
            for (int r = 0; r < 4; ++r) {
                const int idx = mi * 4 + r;
                const float v0 = acc[mi][0][r], v1 = acc[mi][1][r];
                const float v2 = acc[mi][2][r], v3 = acc[mi][3][r];
                const float mx = fmaxf(fmaxf(v0, v1), fmaxf(v2, v3));
                const float mn = fmaxf(m_run[idx], mx);
                const float scale = __expf(m_run[idx] - mn);
                s_run[idx] = s_run[idx] * scale
                           + __expf(v0 - mn) + __expf(v1 - mn)
                           + __expf(v2 - mn) + __expf(v3 - mn);
                m_run[idx] = mn;
            }
    } // ct

    // Cross-lane combine over the 16 column-lanes (same rows share lhi group)
#pragma unroll
    for (int idx = 0; idx < 16; ++idx) {
        float m = m_run[idx], s = s_run[idx];
#pragma unroll
        for (int off = 1; off < 16; off <<= 1) {
            const float mo = __shfl_xor(m, off, 64);
            const float so = __shfl_xor(s, off, 64);
            const float mn = fmaxf(m, mo);
            s = s * __expf(m - mn) + so * __expf(mo - mn);
            m = mn;
        }
        m_run[idx] = m; s_run[idx] = s;
    }

    // One writer lane per 16-lane group; two wc-waves use separate slots.
    if (l15 == 0) {
#pragma unroll
        for (int mi = 0; mi < 4; ++mi)
#pragma unroll
            for (int r = 0; r < 4; ++r) {
                const int row_g = row0 + wr * 64 + mi * 16 + lhi * 4 + r;
                const int slot  = cs * 2 + wc;
                pm[row_g * NPART + slot] = m_run[mi * 4 + r];
                ps[row_g * NPART + slot] = s_run[mi * 4 + r];
            }
    }
}

// Finish: combine partials -> lse, masked mean, scalar out
__global__ void nce_finish(
    const int* __restrict__ tgt,      // int32 tokens (harness converts ints to i32)
    const float* __restrict__ numer,
    const float* __restrict__ pm,
    const float* __restrict__ ps,
    float* __restrict__ out)
{
    const int tid = threadIdx.x;   // 256 threads, 1 block
    float loss = 0.f, cnt = 0.f;

    for (int row = tid; row < N_TOK; row += 256) {
        if (tgt[row] != MASK_ID_V) continue;
        float m = -3.0e38f;
#pragma unroll
        for (int k = 0; k < NPART; ++k) m = fmaxf(m, pm[row * NPART + k]);
        float s = 0.f;
#pragma unroll
        for (int k = 0; k < NPART; ++k)
            s += ps[row * NPART + k] * __expf(pm[row * NPART + k] - m);
        const float lse = m + __logf(s);
        loss += numer[row] - lse;
        cnt  += 1.f;
    }

    __shared__ float sl[256], sc[256];
    sl[tid] = loss; sc[tid] = cnt;
    __syncthreads();
    for (int off = 128; off > 0; off >>= 1) {
        if (tid < off) { sl[tid] += sl[tid + off]; sc[tid] += sc[tid + off]; }
        __syncthreads();
    }
    if (tid == 0) out[0] = -(sl[0] / sc[0]);
}

extern "C" void kernel_launch(void* const* d_in, const int* in_sizes, int n_in,
                              void* d_out, int out_size, void* d_ws, size_t ws_size,
                              hipStream_t stream) {
    (void)in_sizes; (void)n_in; (void)out_size; (void)ws_size;
    const float* x   = (const float*)d_in[0];      // [8,512,1024] f32
    const float* emb = (const float*)d_in[1];      // [8,512,1024] f32
    const int*   tgt = (const int*)d_in[2];        // [8,512] i32
    float* out = (float*)d_out;                    // scalar f32

    // Workspace carve: numer[4096], pm[4096*16], ps[4096*16]  (~540 KB)
    float* numer = (float*)d_ws;
    float* pm    = numer + N_TOK;
    float* ps    = pm + (size_t)N_TOK * NPART;

    dim3 grid(N_TOK / BM, NSLICE);   // 32 x 8 = 256 blocks
    nce_gemm_lse<<<grid, 256, 0, stream>>>(x, emb, numer, pm, ps);
    nce_finish<<<1, 256, 0, stream>>>(tgt, numer, pm, ps, out);
}